// Round 12
// baseline (514.427 us; speedup 1.0000x reference)
//
#include <hip/hip_runtime.h>
#include <hip/hip_bf16.h>
#include <stdint.h>

// FusedMoEBlock R11: fused_in (R10, proven 290us vs 385 separate) +
// SEPARATE moe_down / dense_down (R7-exact; R10's down-fusion regressed,
// likely 128-VGPR occupancy cliff). Everything else R7.
// Layouts: xbK[kblk][t][32], xe[e][kblk][slot][32], act[e][kblk][slot][32],
//          s_actK[kblk][t][32].
// T=2048,H=2048,E=64,I=512,IS=1024,k<=8.
// d_out = [shared_out (T*H f32) | routed (T*H f32)].

#define H_DIM 2048
#define E_NUM 64
#define I_DIM 512
#define IS_DIM 1024
#define CAPR 288
#define TOPK_MAX 8
#define BK 64
#define LDP 68   // B LDS row stride (u16): 34 dwords == 2 mod 32 -> <=2-way

typedef float f32x4 __attribute__((ext_vector_type(4)));
typedef __bf16 bf16x8 __attribute__((ext_vector_type(8)));

__device__ __forceinline__ uint16_t f2bf(float f) {
  union { float f; uint32_t u; } v;
  v.f = f;
  uint32_t r = (v.u + 0x7FFFu + ((v.u >> 16) & 1u)) >> 16;  // RNE
  return (uint16_t)r;
}
__device__ __forceinline__ uint32_t pack2(float a, float b) {
  return (uint32_t)f2bf(a) | ((uint32_t)f2bf(b) << 16);
}
__device__ __forceinline__ float bf2f(uint16_t b) {
  union { uint32_t u; float f; } v;
  v.u = (uint32_t)b << 16;
  return v.f;
}

#define BAR()                                              \
  do {                                                     \
    asm volatile("s_waitcnt lgkmcnt(0)" ::: "memory");     \
    __builtin_amdgcn_s_barrier();                          \
    asm volatile("" ::: "memory");                         \
  } while (0)

// ---------------- router: logits/top-k/buckets; writes xbK (k-blocked) -----
__global__ __launch_bounds__(256) void router_kernel(
    const float* __restrict__ x, const float* __restrict__ gw,
    const int* __restrict__ topk_ptr, int* __restrict__ cnt,
    int* __restrict__ bucket, float* __restrict__ bw,
    uint16_t* __restrict__ xbK, const int T) {
  const int t = blockIdx.x;
  const int tid = threadIdx.x;
  __shared__ float xs[H_DIM];
  __shared__ float logits[E_NUM];
#pragma unroll
  for (int i = 0; i < 2; ++i) {
    int idx = tid + i * 256;
    *(float4*)(&xs[idx * 4]) = *(const float4*)(x + (size_t)t * H_DIM + idx * 4);
  }
  __syncthreads();
  {
    const float* p = &xs[tid * 8];
    uint4 o;
    o.x = pack2(p[0], p[1]);
    o.y = pack2(p[2], p[3]);
    o.z = pack2(p[4], p[5]);
    o.w = pack2(p[6], p[7]);
    *(uint4*)(xbK + (size_t)(tid >> 2) * T * 32 + (size_t)t * 32 +
              (tid & 3) * 8) = o;
  }
  const int lane = tid & 63, wid = tid >> 6;
  float xr[32];
#pragma unroll
  for (int it = 0; it < 32; ++it) xr[it] = xs[lane + 64 * it];
  for (int eo = 0; eo < 16; ++eo) {
    int e = wid + eo * 4;
    const float* g = gw + (size_t)e * H_DIM;
    float acc = 0.f;
#pragma unroll
    for (int it = 0; it < 32; ++it) acc += xr[it] * g[lane + 64 * it];
#pragma unroll
    for (int off = 32; off; off >>= 1) acc += __shfl_xor(acc, off);
    if (lane == 0) logits[e] = acc;
  }
  __syncthreads();
  if (wid == 0) {
    int k = topk_ptr[0];
    if (k > TOPK_MAX) k = TOPK_MAX;
    // sigmoid; pre-topk normalize is scale-invariant -> skipped
    float v = 1.f / (1.f + expf(-logits[lane]));
    float s = 0.f, myw = 0.f;
    int mye = 0;
    for (int j = 0; j < k; ++j) {
      float m = v;
      int mi = lane;
#pragma unroll
      for (int off = 32; off; off >>= 1) {
        float ov = __shfl_xor(m, off);
        int oi = __shfl_xor(mi, off);
        if (ov > m || (ov == m && oi < mi)) { m = ov; mi = oi; }
      }
      if (lane == j) { myw = m; mye = mi; }
      if (lane == mi) v = -1e30f;
      s += m;
    }
    if (lane < k) {
      float w = myw / s;
      int pos = atomicAdd(&cnt[mye], 1);
      if (pos < CAPR) {
        bucket[mye * CAPR + pos] = t * 8 + lane;
        bw[mye * CAPR + pos] = w;
      }
    }
  }
}

// ---------------- gather: xe[e][kblk][slot][32] = xbK[kblk][token][32] -----
__global__ __launch_bounds__(256) void gather_xe(
    const uint16_t* __restrict__ xbK, const int* __restrict__ cnt,
    const int* __restrict__ bucket, uint16_t* __restrict__ xe, const int T) {
  const int e = blockIdx.x;
  const int kgrp = blockIdx.y & 15, sgrp = blockIdx.y >> 4;
  const int tid = threadIdx.x;
  const int slot = sgrp * 64 + (tid & 63);
  const int kblk = kgrp * 4 + (tid >> 6);
  const int n_e = min(cnt[e], CAPR);
  if (slot >= n_e) return;
  const int t = bucket[e * CAPR + slot] >> 3;
  const uint4* src = (const uint4*)(xbK + (size_t)kblk * T * 32 + (size_t)t * 32);
  uint4* dst = (uint4*)(xe + (size_t)e * (64 * CAPR * 32) +
                        (size_t)kblk * (CAPR * 32) + (size_t)slot * 32);
#pragma unroll
  for (int j = 0; j < 4; ++j) dst[j] = src[j];
}

// ---------------- gate+up body (R7-exact, BN=32) ----------------
template <int BM, bool GATHER>
__device__ __forceinline__ void ffn_in_body(
    uint16_t (*Bgs)[32][LDP], uint16_t (*Bus)[32][LDP],
    const uint16_t* __restrict__ A0, const float* __restrict__ Wg,
    const float* __restrict__ Wu, uint16_t* __restrict__ actO,
    const int* __restrict__ cnt, const int K, const int ldb, const int SLOTS,
    const int bid) {
  constexpr int MF = BM / 64;
  constexpr int NF = 2;

  int e = 0, nt, mt0, mtE, n_e;
  const float *Bg, *Bu;
  const uint16_t* AE;
  uint16_t* outE;
  if constexpr (GATHER) {
    e = bid & 63;   // consecutive bid -> consecutive e -> XCD e%8
    nt = bid >> 6;
    n_e = min(cnt[e], CAPR);
    mt0 = 0;
    mtE = (n_e + BM - 1) / BM;
    const size_t wo = (size_t)e * K * ldb;
    Bg = Wg + wo;
    Bu = Wu + wo;
    AE = A0 + (size_t)e * (64 * CAPR * 32);
    outE = actO + (size_t)e * ((I_DIM / 32) * CAPR * 32);
  } else {
    nt = bid & 31;        // IS_DIM/32 = 32 strips
    mt0 = bid >> 5;
    mtE = mt0 + 1;
    n_e = 1 << 30;
    Bg = Wg;
    Bu = Wu;
    AE = A0;
    outE = actO;
  }
  if (mt0 * BM >= n_e) return;

  const int tid = threadIdx.x;
  const int cg4 = (tid & 7) * 4, kp = tid >> 3;
  const float* bgp = Bg + (size_t)(2 * kp) * ldb + nt * 32 + cg4;
  const float* bup = Bu + (size_t)(2 * kp) * ldb + nt * 32 + cg4;

  const int lane = tid & 63, wid = tid >> 6;
  const int fr = lane & 15, kg = lane >> 4;
  const int wrow = wid * (BM / 4);
  const size_t ldA = (size_t)SLOTS * 32;

  float4 g0, g1, u0, u1;
  const int NS = K / BK;

  for (int mt = mt0; mt < mtE; ++mt) {
    const uint16_t* ab[MF];
#pragma unroll
    for (int mf = 0; mf < MF; ++mf)
      ab[mf] = AE + (size_t)(mt * BM + wrow + mf * 16 + fr) * 32 + kg * 8;

    f32x4 accg[MF][NF] = {};
    f32x4 accu[MF][NF] = {};

    g0 = *(const float4*)bgp;
    g1 = *(const float4*)(bgp + ldb);
    u0 = *(const float4*)bup;
    u1 = *(const float4*)(bup + ldb);
    {
      const int k2 = 2 * kp;
      *(uint32_t*)(&Bgs[0][cg4 + 0][k2]) = pack2(g0.x, g1.x);
      *(uint32_t*)(&Bgs[0][cg4 + 1][k2]) = pack2(g0.y, g1.y);
      *(uint32_t*)(&Bgs[0][cg4 + 2][k2]) = pack2(g0.z, g1.z);
      *(uint32_t*)(&Bgs[0][cg4 + 3][k2]) = pack2(g0.w, g1.w);
      *(uint32_t*)(&Bus[0][cg4 + 0][k2]) = pack2(u0.x, u1.x);
      *(uint32_t*)(&Bus[0][cg4 + 1][k2]) = pack2(u0.y, u1.y);
      *(uint32_t*)(&Bus[0][cg4 + 2][k2]) = pack2(u0.z, u1.z);
      *(uint32_t*)(&Bus[0][cg4 + 3][k2]) = pack2(u0.w, u1.w);
    }
    if (NS > 1) {
      const float* g = bgp + (size_t)BK * ldb;
      g0 = *(const float4*)g;
      g1 = *(const float4*)(g + ldb);
      const float* u = bup + (size_t)BK * ldb;
      u0 = *(const float4*)u;
      u1 = *(const float4*)(u + ldb);
    }
    BAR();

    int b = 0;
    for (int s = 0; s < NS; ++s) {
      uint4 a[MF][2];
#pragma unroll
      for (int mf = 0; mf < MF; ++mf)
#pragma unroll
        for (int sl = 0; sl < 2; ++sl)
          a[mf][sl] = *(const uint4*)(ab[mf] + (size_t)(2 * s + sl) * ldA);
      if (s + 1 < NS) {
        const int k2 = 2 * kp;
        *(uint32_t*)(&Bgs[b ^ 1][cg4 + 0][k2]) = pack2(g0.x, g1.x);
        *(uint32_t*)(&Bgs[b ^ 1][cg4 + 1][k2]) = pack2(g0.y, g1.y);
        *(uint32_t*)(&Bgs[b ^ 1][cg4 + 2][k2]) = pack2(g0.z, g1.z);
        *(uint32_t*)(&Bgs[b ^ 1][cg4 + 3][k2]) = pack2(g0.w, g1.w);
        *(uint32_t*)(&Bus[b ^ 1][cg4 + 0][k2]) = pack2(u0.x, u1.x);
        *(uint32_t*)(&Bus[b ^ 1][cg4 + 1][k2]) = pack2(u0.y, u1.y);
        *(uint32_t*)(&Bus[b ^ 1][cg4 + 2][k2]) = pack2(u0.z, u1.z);
        *(uint32_t*)(&Bus[b ^ 1][cg4 + 3][k2]) = pack2(u0.w, u1.w);
      }
      if (s + 2 < NS) {
        const float* g = bgp + (size_t)((s + 2) * BK) * ldb;
        g0 = *(const float4*)g;
        g1 = *(const float4*)(g + ldb);
        const float* u = bup + (size_t)((s + 2) * BK) * ldb;
        u0 = *(const float4*)u;
        u1 = *(const float4*)(u + ldb);
      }
#pragma unroll
      for (int sl = 0; sl < 2; ++sl)
#pragma unroll
        for (int nf = 0; nf < NF; ++nf) {
          const bf16x8 bg = __builtin_bit_cast(
              bf16x8, *(const uint4*)(&Bgs[b][nf * 16 + fr][kg * 8 + sl * 32]));
          const bf16x8 bu = __builtin_bit_cast(
              bf16x8, *(const uint4*)(&Bus[b][nf * 16 + fr][kg * 8 + sl * 32]));
#pragma unroll
          for (int mf = 0; mf < MF; ++mf) {
            const bf16x8 af = __builtin_bit_cast(bf16x8, a[mf][sl]);
            accg[mf][nf] = __builtin_amdgcn_mfma_f32_16x16x32_bf16(
                af, bg, accg[mf][nf], 0, 0, 0);
            accu[mf][nf] = __builtin_amdgcn_mfma_f32_16x16x32_bf16(
                af, bu, accu[mf][nf], 0, 0, 0);
          }
        }
      BAR();
      b ^= 1;
    }

#pragma unroll
    for (int mf = 0; mf < MF; ++mf)
#pragma unroll
      for (int rr = 0; rr < 4; ++rr) {
        const int slot = mt * BM + wrow + mf * 16 + kg * 4 + rr;
        if (slot < n_e) {
          uint16_t* op = outE + (size_t)nt * ldA + (size_t)slot * 32 + fr;
#pragma unroll
          for (int nf = 0; nf < NF; ++nf) {
            const float g = accg[mf][nf][rr], u = accu[mf][nf][rr];
            op[nf * 16] = f2bf(g / (1.f + expf(-g)) * u);
          }
        }
      }
  }
}

// fused: blocks [0,1024) = grouped gate+up; [1024,1536) = shared gate+up
__global__ __launch_bounds__(256) void fused_in(
    const uint16_t* __restrict__ xe, const float* __restrict__ Wg,
    const float* __restrict__ Wu, uint16_t* __restrict__ act,
    const int* __restrict__ cnt,
    const uint16_t* __restrict__ xbK, const float* __restrict__ sWg,
    const float* __restrict__ sWu, uint16_t* __restrict__ s_actK, const int T) {
  __shared__ uint16_t Bgs[2][32][LDP];
  __shared__ uint16_t Bus[2][32][LDP];
  const int bx = blockIdx.x;
  if (bx < E_NUM * (I_DIM / 32)) {
    ffn_in_body<256, true>(Bgs, Bus, xe, Wg, Wu, act, cnt, H_DIM, I_DIM, CAPR,
                           bx);
  } else {
    ffn_in_body<128, false>(Bgs, Bus, xbK, sWg, sWu, s_actK, nullptr, H_DIM,
                            IS_DIM, T, bx - E_NUM * (I_DIM / 32));
  }
}

// ---------------- down body (R7-exact, BN=64) ----------------
template <int BM, bool GATHER>
__device__ __forceinline__ void ffn_down_body(
    uint16_t (*Bs)[64][LDP], const uint16_t* __restrict__ A0,
    const float* __restrict__ Wd, void* __restrict__ outp,
    const int* __restrict__ cnt, const int* __restrict__ bucket,
    const float* __restrict__ bw, const int K, const int SLOTS, const int bid) {
  constexpr int MF = BM / 64;
  constexpr int NF = 4;

  int e = 0, nt, mt0, mtE, n_e;
  const float* Bd;
  const uint16_t* AE;
  if constexpr (GATHER) {
    e = bid & 63;
    nt = bid >> 6;
    n_e = min(cnt[e], CAPR);
    mt0 = 0;
    mtE = (n_e + BM - 1) / BM;
    AE = A0 + (size_t)e * ((I_DIM / 32) * CAPR * 32);
    Bd = Wd + (size_t)e * K * H_DIM;
  } else {
    nt = bid & 31;       // H_DIM/64 = 32 strips
    mt0 = bid >> 5;
    mtE = mt0 + 1;
    n_e = 1 << 30;
    AE = A0;
    Bd = Wd;
  }
  if (mt0 * BM >= n_e) return;

  const int tid = threadIdx.x;
  const int cg4 = (tid & 15) * 4, kp = tid >> 4;
  const float* bdp = Bd + (size_t)(2 * kp) * H_DIM + nt * 64 + cg4;

  const int lane = tid & 63, wid = tid >> 6;
  const int fr = lane & 15, kg = lane >> 4;
  const int wrow = wid * (BM / 4);
  const size_t ldA = (size_t)SLOTS * 32;

  float4 d0[2], d1[2];
  const int NS = K / BK;

  for (int mt = mt0; mt < mtE; ++mt) {
    const uint16_t* ab[MF];
#pragma unroll
    for (int mf = 0; mf < MF; ++mf)
      ab[mf] = AE + (size_t)(mt * BM + wrow + mf * 16 + fr) * 32 + kg * 8;

    f32x4 acc[MF][NF] = {};

#pragma unroll
    for (int pp = 0; pp < 2; ++pp) {
      const float* d = bdp + (size_t)(2 * pp * 16) * H_DIM;
      d0[pp] = *(const float4*)d;
      d1[pp] = *(const float4*)(d + H_DIM);
    }
#pragma unroll
    for (int pp = 0; pp < 2; ++pp) {
      const int k2 = 2 * (kp + pp * 16);
      *(uint32_t*)(&Bs[0][cg4 + 0][k2]) = pack2(d0[pp].x, d1[pp].x);
      *(uint32_t*)(&Bs[0][cg4 + 1][k2]) = pack2(d0[pp].y, d1[pp].y);
      *(uint32_t*)(&Bs[0][cg4 + 2][k2]) = pack2(d0[pp].z, d1[pp].z);
      *(uint32_t*)(&Bs[0][cg4 + 3][k2]) = pack2(d0[pp].w, d1[pp].w);
    }
    if (NS > 1) {
#pragma unroll
      for (int pp = 0; pp < 2; ++pp) {
        const float* d = bdp + (size_t)(BK + 2 * pp * 16) * H_DIM;
        d0[pp] = *(const float4*)d;
        d1[pp] = *(const float4*)(d + H_DIM);
      }
    }
    BAR();

    int b = 0;
    for (int s = 0; s < NS; ++s) {
      uint4 a[MF][2];
#pragma unroll
      for (int mf = 0; mf < MF; ++mf)
#pragma unroll
        for (int sl = 0; sl < 2; ++sl)
          a[mf][sl] = *(const uint4*)(ab[mf] + (size_t)(2 * s + sl) * ldA);
      if (s + 1 < NS) {
#pragma unroll
        for (int pp = 0; pp < 2; ++pp) {
          const int k2 = 2 * (kp + pp * 16);
          *(uint32_t*)(&Bs[b ^ 1][cg4 + 0][k2]) = pack2(d0[pp].x, d1[pp].x);
          *(uint32_t*)(&Bs[b ^ 1][cg4 + 1][k2]) = pack2(d0[pp].y, d1[pp].y);
          *(uint32_t*)(&Bs[b ^ 1][cg4 + 2][k2]) = pack2(d0[pp].z, d1[pp].z);
          *(uint32_t*)(&Bs[b ^ 1][cg4 + 3][k2]) = pack2(d0[pp].w, d1[pp].w);
        }
      }
      if (s + 2 < NS) {
#pragma unroll
        for (int pp = 0; pp < 2; ++pp) {
          const float* d = bdp + (size_t)((s + 2) * BK + 2 * pp * 16) * H_DIM;
          d0[pp] = *(const float4*)d;
          d1[pp] = *(const float4*)(d + H_DIM);
        }
      }
#pragma unroll
      for (int sl = 0; sl < 2; ++sl)
#pragma unroll
        for (int nf = 0; nf < NF; ++nf) {
          const bf16x8 bf_ = __builtin_bit_cast(
              bf16x8, *(const uint4*)(&Bs[b][nf * 16 + fr][kg * 8 + sl * 32]));
#pragma unroll
          for (int mf = 0; mf < MF; ++mf) {
            const bf16x8 af = __builtin_bit_cast(bf16x8, a[mf][sl]);
            acc[mf][nf] = __builtin_amdgcn_mfma_f32_16x16x32_bf16(
                af, bf_, acc[mf][nf], 0, 0, 0);
          }
        }
      BAR();
      b ^= 1;
    }

    const int col0 = nt * 64 + fr;
#pragma unroll
    for (int mf = 0; mf < MF; ++mf)
#pragma unroll
      for (int rr = 0; rr < 4; ++rr) {
        const int slot = mt * BM + wrow + mf * 16 + kg * 4 + rr;
        if constexpr (GATHER) {
          if (slot < n_e) {
            const int bv = bucket[e * CAPR + slot];
            const float w = bw[e * CAPR + slot];
            uint16_t* yb = (uint16_t*)outp + (size_t)bv * H_DIM + col0;
#pragma unroll
            for (int nf = 0; nf < NF; ++nf)
              yb[nf * 16] = f2bf(w * acc[mf][nf][rr]);
          }
        } else {
          float* op = (float*)outp + (size_t)slot * H_DIM + col0;
#pragma unroll
          for (int nf = 0; nf < NF; ++nf) op[nf * 16] = acc[mf][nf][rr];
        }
      }
  }
}

// separate down kernels (R7 behavior)
__global__ __launch_bounds__(256) void moe_down_k(
    const uint16_t* __restrict__ act, const float* __restrict__ Wd,
    uint16_t* __restrict__ ybuf, const int* __restrict__ cnt,
    const int* __restrict__ bucket, const float* __restrict__ bw) {
  __shared__ uint16_t Bs[2][64][LDP];
  ffn_down_body<256, true>(Bs, act, Wd, (void*)ybuf, cnt, bucket, bw, I_DIM,
                           CAPR, blockIdx.x);
}
__global__ __launch_bounds__(256) void dense_down_k(
    const uint16_t* __restrict__ s_actK, const float* __restrict__ sWd,
    float* __restrict__ shared_out, const int T) {
  __shared__ uint16_t Bs[2][64][LDP];
  ffn_down_body<128, false>(Bs, s_actK, sWd, (void*)shared_out, nullptr,
                            nullptr, nullptr, IS_DIM, T, blockIdx.x);
}

// ---------------- combine: routed[t] = sum_{j<k} ybuf[t*8+j] ----------------
__global__ __launch_bounds__(256) void combine_kernel(
    const uint16_t* __restrict__ ybuf, const int* __restrict__ topk_ptr,
    float* __restrict__ routed) {
  const int t = blockIdx.x;
  const int tid = threadIdx.x;
  int k = topk_ptr[0];
  if (k > TOPK_MAX) k = TOPK_MAX;
  float acc[8] = {};
  const uint16_t* base = ybuf + (size_t)t * 8 * H_DIM + tid * 8;
  for (int j = 0; j < k; ++j) {
    uint4 v = *(const uint4*)(base + (size_t)j * H_DIM);
    const uint16_t* h = (const uint16_t*)&v;
#pragma unroll
    for (int i = 0; i < 8; ++i) acc[i] += bf2f(h[i]);
  }
  float* op = routed + (size_t)t * H_DIM + tid * 8;
  *(float4*)op = make_float4(acc[0], acc[1], acc[2], acc[3]);
  *(float4*)(op + 4) = make_float4(acc[4], acc[5], acc[6], acc[7]);
}

extern "C" void kernel_launch(void* const* d_in, const int* in_sizes, int n_in,
                              void* d_out, int out_size, void* d_ws, size_t ws_size,
                              hipStream_t stream) {
  const float* x = (const float*)d_in[0];
  const float* gw = (const float*)d_in[1];
  const float* w_gate = (const float*)d_in[2];
  const float* w_up = (const float*)d_in[3];
  const float* w_down = (const float*)d_in[4];
  const float* sw_gate = (const float*)d_in[5];
  const float* sw_up = (const float*)d_in[6];
  const float* sw_down = (const float*)d_in[7];
  const int* topk = (const int*)d_in[8];
  const int T = in_sizes[0] / H_DIM;  // 2048

  float* shared_out = (float*)d_out;
  float* routed = shared_out + (size_t)T * H_DIM;

  char* ws = (char*)d_ws;
  size_t off = 0;
  auto take = [&](size_t b) {
    char* p = ws + off;
    off += (b + 255) & ~(size_t)255;
    return p;
  };
  uint16_t* xbK = (uint16_t*)take((size_t)T * H_DIM * 2);                      // 8.4 MB
  int* cnt = (int*)take(E_NUM * 4);
  int* bucket = (int*)take((size_t)E_NUM * CAPR * 4);
  float* bw = (float*)take((size_t)E_NUM * CAPR * 4);
  uint16_t* xe = (uint16_t*)take((size_t)E_NUM * 64 * CAPR * 32 * 2 + 65536);  // 75.5 MB
  uint16_t* act = (uint16_t*)take((size_t)E_NUM * 16 * CAPR * 32 * 2 + 65536); // 18.9 MB
  uint16_t* s_actK = (uint16_t*)take((size_t)(IS_DIM / 32) * T * 32 * 2);      // 4.2 MB
  uint16_t* ybuf = (uint16_t*)take((size_t)T * 8 * H_DIM * 2);                 // 67 MB

  hipMemsetAsync(cnt, 0, E_NUM * 4, stream);

  router_kernel<<<T, 256, 0, stream>>>(x, gw, topk, cnt, bucket, bw, xbK, T);
  gather_xe<<<dim3(E_NUM, 16 * ((CAPR + 63) / 64)), 256, 0, stream>>>(
      xbK, cnt, bucket, xe, T);

  // co-run grouped (HBM-bound) and shared (L3-bound) gate+up  [R10: 290us]
  fused_in<<<E_NUM * (I_DIM / 32) + (IS_DIM / 32) * (T / 128), 256, 0, stream>>>(
      xe, w_gate, w_up, act, cnt, xbK, sw_gate, sw_up, s_actK, T);
  // separate downs (R7 behavior)
  moe_down_k<<<E_NUM * (H_DIM / 64), 256, 0, stream>>>(act, w_down, ybuf, cnt,
                                                       bucket, bw);
  dense_down_k<<<(H_DIM / 64) * (T / 128), 256, 0, stream>>>(s_actK, sw_down,
                                                             shared_out, T);
  combine_kernel<<<T, 256, 0, stream>>>(ybuf, topk, routed);
}

// Round 13
// 471.377 us; speedup vs baseline: 1.0913x; 1.0913x over previous
//
#include <hip/hip_runtime.h>
#include <hip/hip_bf16.h>
#include <stdint.h>

// FusedMoEBlock R12: pure R7 structure (best measured baseline, 440us),
// with two pressure-reducing edits:
//  (1) gather_xe removed -- moe_in A-fragments read xbK via bucket indirection
//      (same cache-line count: rows are 64B k-blocked chunks).
//  (2) B-staging pack f32->bf16 via single v_perm_b32 truncation (builtin,
//      no asm, no register pinning) instead of 11-op RNE pack.
// Layouts: xbK[kblk][t][32], act[e][kblk][slot][32], s_actK[kblk][t][32].
// T=2048,H=2048,E=64,I=512,IS=1024,k<=8.
// d_out = [shared_out (T*H f32) | routed (T*H f32)].

#define H_DIM 2048
#define E_NUM 64
#define I_DIM 512
#define IS_DIM 1024
#define CAPR 288
#define TOPK_MAX 8
#define BK 64
#define LDP 68   // B LDS row stride (u16): 34 dwords == 2 mod 32 -> <=2-way

typedef float f32x4 __attribute__((ext_vector_type(4)));
typedef __bf16 bf16x8 __attribute__((ext_vector_type(8)));

__device__ __forceinline__ uint16_t f2bf(float f) {
  union { float f; uint32_t u; } v;
  v.f = f;
  uint32_t r = (v.u + 0x7FFFu + ((v.u >> 16) & 1u)) >> 16;  // RNE
  return (uint16_t)r;
}
__device__ __forceinline__ uint32_t pack2(float a, float b) {  // RNE pack
  return (uint32_t)f2bf(a) | ((uint32_t)f2bf(b) << 16);
}
// truncating pack: dst = hi16(b) : hi16(a), single v_perm_b32
__device__ __forceinline__ uint32_t pk2t(float a, float b) {
  return __builtin_amdgcn_perm(__builtin_bit_cast(uint32_t, b),
                               __builtin_bit_cast(uint32_t, a), 0x07060302u);
}
__device__ __forceinline__ float bf2f(uint16_t b) {
  union { uint32_t u; float f; } v;
  v.u = (uint32_t)b << 16;
  return v.f;
}

#define BAR()                                              \
  do {                                                     \
    asm volatile("s_waitcnt lgkmcnt(0)" ::: "memory");     \
    __builtin_amdgcn_s_barrier();                          \
    asm volatile("" ::: "memory");                         \
  } while (0)

// ---------------- router: logits/top-k/buckets; writes xbK (k-blocked) -----
__global__ __launch_bounds__(256) void router_kernel(
    const float* __restrict__ x, const float* __restrict__ gw,
    const int* __restrict__ topk_ptr, int* __restrict__ cnt,
    int* __restrict__ bucket, float* __restrict__ bw,
    uint16_t* __restrict__ xbK, const int T) {
  const int t = blockIdx.x;
  const int tid = threadIdx.x;
  __shared__ float xs[H_DIM];
  __shared__ float logits[E_NUM];
#pragma unroll
  for (int i = 0; i < 2; ++i) {
    int idx = tid + i * 256;
    *(float4*)(&xs[idx * 4]) = *(const float4*)(x + (size_t)t * H_DIM + idx * 4);
  }
  __syncthreads();
  {
    const float* p = &xs[tid * 8];
    uint4 o;
    o.x = pack2(p[0], p[1]);
    o.y = pack2(p[2], p[3]);
    o.z = pack2(p[4], p[5]);
    o.w = pack2(p[6], p[7]);
    *(uint4*)(xbK + (size_t)(tid >> 2) * T * 32 + (size_t)t * 32 +
              (tid & 3) * 8) = o;
  }
  const int lane = tid & 63, wid = tid >> 6;
  float xr[32];
#pragma unroll
  for (int it = 0; it < 32; ++it) xr[it] = xs[lane + 64 * it];
  for (int eo = 0; eo < 16; ++eo) {
    int e = wid + eo * 4;
    const float* g = gw + (size_t)e * H_DIM;
    float acc = 0.f;
#pragma unroll
    for (int it = 0; it < 32; ++it) acc += xr[it] * g[lane + 64 * it];
#pragma unroll
    for (int off = 32; off; off >>= 1) acc += __shfl_xor(acc, off);
    if (lane == 0) logits[e] = acc;
  }
  __syncthreads();
  if (wid == 0) {
    int k = topk_ptr[0];
    if (k > TOPK_MAX) k = TOPK_MAX;
    // sigmoid; pre-topk normalize is scale-invariant -> skipped
    float v = 1.f / (1.f + expf(-logits[lane]));
    float s = 0.f, myw = 0.f;
    int mye = 0;
    for (int j = 0; j < k; ++j) {
      float m = v;
      int mi = lane;
#pragma unroll
      for (int off = 32; off; off >>= 1) {
        float ov = __shfl_xor(m, off);
        int oi = __shfl_xor(mi, off);
        if (ov > m || (ov == m && oi < mi)) { m = ov; mi = oi; }
      }
      if (lane == j) { myw = m; mye = mi; }
      if (lane == mi) v = -1e30f;
      s += m;
    }
    if (lane < k) {
      float w = myw / s;
      int pos = atomicAdd(&cnt[mye], 1);
      if (pos < CAPR) {
        bucket[mye * CAPR + pos] = t * 8 + lane;
        bw[mye * CAPR + pos] = w;
      }
    }
  }
}

// ---------------- gate+up body (R7 schedule, BN=32) ----------------
// GATHER: A rows come from xbK via bucket indirection (no xe buffer).
template <int BM, bool GATHER>
__device__ __forceinline__ void ffn_in_body(
    uint16_t (*Bgs)[32][LDP], uint16_t (*Bus)[32][LDP],
    const uint16_t* __restrict__ A0, const float* __restrict__ Wg,
    const float* __restrict__ Wu, uint16_t* __restrict__ actO,
    const int* __restrict__ cnt, const int* __restrict__ bucket,
    const int K, const int ldb, const int T, const int bid) {
  constexpr int MF = BM / 64;
  constexpr int NF = 2;

  int e = 0, nt, mt0, mtE, n_e;
  const float *Bg, *Bu;
  uint16_t* outE;
  size_t ldOut;
  if constexpr (GATHER) {
    e = bid & 63;   // consecutive bid -> consecutive e
    nt = bid >> 6;
    n_e = min(cnt[e], CAPR);
    mt0 = 0;
    mtE = (n_e + BM - 1) / BM;
    const size_t wo = (size_t)e * K * ldb;
    Bg = Wg + wo;
    Bu = Wu + wo;
    outE = actO + (size_t)e * ((I_DIM / 32) * CAPR * 32);
    ldOut = (size_t)CAPR * 32;
  } else {
    nt = bid & 31;        // IS_DIM/32 = 32 strips
    mt0 = bid >> 5;
    mtE = mt0 + 1;
    n_e = 1 << 30;
    Bg = Wg;
    Bu = Wu;
    outE = actO;
    ldOut = (size_t)T * 32;
  }
  if (mt0 * BM >= n_e) return;

  const int tid = threadIdx.x;
  const int cg4 = (tid & 7) * 4, kp = tid >> 3;
  const float* bgp = Bg + (size_t)(2 * kp) * ldb + nt * 32 + cg4;
  const float* bup = Bu + (size_t)(2 * kp) * ldb + nt * 32 + cg4;

  const int lane = tid & 63, wid = tid >> 6;
  const int fr = lane & 15, kg = lane >> 4;
  const int wrow = wid * (BM / 4);
  const size_t ldA = (size_t)T * 32;  // A k-step stride (xbK layout)

  float4 g0, g1, u0, u1;
  const int NS = K / BK;

  for (int mt = mt0; mt < mtE; ++mt) {
    const uint16_t* ab[MF];
#pragma unroll
    for (int mf = 0; mf < MF; ++mf) {
      const int slot = mt * BM + wrow + mf * 16 + fr;
      if constexpr (GATHER) {
        const int idx = slot < n_e ? slot : 0;
        const int t = bucket[e * CAPR + idx] >> 3;
        ab[mf] = A0 + (size_t)t * 32 + kg * 8;
      } else {
        ab[mf] = A0 + (size_t)slot * 32 + kg * 8;
      }
    }

    f32x4 accg[MF][NF] = {};
    f32x4 accu[MF][NF] = {};

    g0 = *(const float4*)bgp;
    g1 = *(const float4*)(bgp + ldb);
    u0 = *(const float4*)bup;
    u1 = *(const float4*)(bup + ldb);
    {
      const int k2 = 2 * kp;
      *(uint32_t*)(&Bgs[0][cg4 + 0][k2]) = pk2t(g0.x, g1.x);
      *(uint32_t*)(&Bgs[0][cg4 + 1][k2]) = pk2t(g0.y, g1.y);
      *(uint32_t*)(&Bgs[0][cg4 + 2][k2]) = pk2t(g0.z, g1.z);
      *(uint32_t*)(&Bgs[0][cg4 + 3][k2]) = pk2t(g0.w, g1.w);
      *(uint32_t*)(&Bus[0][cg4 + 0][k2]) = pk2t(u0.x, u1.x);
      *(uint32_t*)(&Bus[0][cg4 + 1][k2]) = pk2t(u0.y, u1.y);
      *(uint32_t*)(&Bus[0][cg4 + 2][k2]) = pk2t(u0.z, u1.z);
      *(uint32_t*)(&Bus[0][cg4 + 3][k2]) = pk2t(u0.w, u1.w);
    }
    if (NS > 1) {
      const float* g = bgp + (size_t)BK * ldb;
      g0 = *(const float4*)g;
      g1 = *(const float4*)(g + ldb);
      const float* u = bup + (size_t)BK * ldb;
      u0 = *(const float4*)u;
      u1 = *(const float4*)(u + ldb);
    }
    BAR();

    int b = 0;
    for (int s = 0; s < NS; ++s) {
      uint4 a[MF][2];
#pragma unroll
      for (int mf = 0; mf < MF; ++mf)
#pragma unroll
        for (int sl = 0; sl < 2; ++sl)
          a[mf][sl] = *(const uint4*)(ab[mf] + (size_t)(2 * s + sl) * ldA);
      if (s + 1 < NS) {
        const int k2 = 2 * kp;
        *(uint32_t*)(&Bgs[b ^ 1][cg4 + 0][k2]) = pk2t(g0.x, g1.x);
        *(uint32_t*)(&Bgs[b ^ 1][cg4 + 1][k2]) = pk2t(g0.y, g1.y);
        *(uint32_t*)(&Bgs[b ^ 1][cg4 + 2][k2]) = pk2t(g0.z, g1.z);
        *(uint32_t*)(&Bgs[b ^ 1][cg4 + 3][k2]) = pk2t(g0.w, g1.w);
        *(uint32_t*)(&Bus[b ^ 1][cg4 + 0][k2]) = pk2t(u0.x, u1.x);
        *(uint32_t*)(&Bus[b ^ 1][cg4 + 1][k2]) = pk2t(u0.y, u1.y);
        *(uint32_t*)(&Bus[b ^ 1][cg4 + 2][k2]) = pk2t(u0.z, u1.z);
        *(uint32_t*)(&Bus[b ^ 1][cg4 + 3][k2]) = pk2t(u0.w, u1.w);
      }
      if (s + 2 < NS) {
        const float* g = bgp + (size_t)((s + 2) * BK) * ldb;
        g0 = *(const float4*)g;
        g1 = *(const float4*)(g + ldb);
        const float* u = bup + (size_t)((s + 2) * BK) * ldb;
        u0 = *(const float4*)u;
        u1 = *(const float4*)(u + ldb);
      }
#pragma unroll
      for (int sl = 0; sl < 2; ++sl)
#pragma unroll
        for (int nf = 0; nf < NF; ++nf) {
          const bf16x8 bg = __builtin_bit_cast(
              bf16x8, *(const uint4*)(&Bgs[b][nf * 16 + fr][kg * 8 + sl * 32]));
          const bf16x8 bu = __builtin_bit_cast(
              bf16x8, *(const uint4*)(&Bus[b][nf * 16 + fr][kg * 8 + sl * 32]));
#pragma unroll
          for (int mf = 0; mf < MF; ++mf) {
            const bf16x8 af = __builtin_bit_cast(bf16x8, a[mf][sl]);
            accg[mf][nf] = __builtin_amdgcn_mfma_f32_16x16x32_bf16(
                af, bg, accg[mf][nf], 0, 0, 0);
            accu[mf][nf] = __builtin_amdgcn_mfma_f32_16x16x32_bf16(
                af, bu, accu[mf][nf], 0, 0, 0);
          }
        }
      BAR();
      b ^= 1;
    }

#pragma unroll
    for (int mf = 0; mf < MF; ++mf)
#pragma unroll
      for (int rr = 0; rr < 4; ++rr) {
        const int slot = mt * BM + wrow + mf * 16 + kg * 4 + rr;
        if (slot < n_e) {
          uint16_t* op = outE + (size_t)nt * ldOut + (size_t)slot * 32 + fr;
#pragma unroll
          for (int nf = 0; nf < NF; ++nf) {
            const float g = accg[mf][nf][rr], u = accu[mf][nf][rr];
            op[nf * 16] = f2bf(g / (1.f + expf(-g)) * u);
          }
        }
      }
  }
}

__global__ __launch_bounds__(256) void moe_in_k(
    const uint16_t* __restrict__ xbK, const float* __restrict__ Wg,
    const float* __restrict__ Wu, uint16_t* __restrict__ act,
    const int* __restrict__ cnt, const int* __restrict__ bucket, const int T) {
  __shared__ uint16_t Bgs[2][32][LDP];
  __shared__ uint16_t Bus[2][32][LDP];
  ffn_in_body<256, true>(Bgs, Bus, xbK, Wg, Wu, act, cnt, bucket, H_DIM, I_DIM,
                         T, blockIdx.x);
}
__global__ __launch_bounds__(256) void dense_in_k(
    const uint16_t* __restrict__ xbK, const float* __restrict__ sWg,
    const float* __restrict__ sWu, uint16_t* __restrict__ s_actK, const int T) {
  __shared__ uint16_t Bgs[2][32][LDP];
  __shared__ uint16_t Bus[2][32][LDP];
  ffn_in_body<128, false>(Bgs, Bus, xbK, sWg, sWu, s_actK, nullptr, nullptr,
                          H_DIM, IS_DIM, T, blockIdx.x);
}

// ---------------- down body (R7 schedule, BN=64) ----------------
template <int BM, bool GATHER>
__device__ __forceinline__ void ffn_down_body(
    uint16_t (*Bs)[64][LDP], const uint16_t* __restrict__ A0,
    const float* __restrict__ Wd, void* __restrict__ outp,
    const int* __restrict__ cnt, const int* __restrict__ bucket,
    const float* __restrict__ bw, const int K, const int SLOTS, const int bid) {
  constexpr int MF = BM / 64;
  constexpr int NF = 4;

  int e = 0, nt, mt0, mtE, n_e;
  const float* Bd;
  const uint16_t* AE;
  if constexpr (GATHER) {
    e = bid & 63;
    nt = bid >> 6;
    n_e = min(cnt[e], CAPR);
    mt0 = 0;
    mtE = (n_e + BM - 1) / BM;
    AE = A0 + (size_t)e * ((I_DIM / 32) * CAPR * 32);
    Bd = Wd + (size_t)e * K * H_DIM;
  } else {
    nt = bid & 31;       // H_DIM/64 = 32 strips
    mt0 = bid >> 5;
    mtE = mt0 + 1;
    n_e = 1 << 30;
    AE = A0;
    Bd = Wd;
  }
  if (mt0 * BM >= n_e) return;

  const int tid = threadIdx.x;
  const int cg4 = (tid & 15) * 4, kp = tid >> 4;
  const float* bdp = Bd + (size_t)(2 * kp) * H_DIM + nt * 64 + cg4;

  const int lane = tid & 63, wid = tid >> 6;
  const int fr = lane & 15, kg = lane >> 4;
  const int wrow = wid * (BM / 4);
  const size_t ldA = (size_t)SLOTS * 32;

  float4 d0[2], d1[2];
  const int NS = K / BK;

  for (int mt = mt0; mt < mtE; ++mt) {
    const uint16_t* ab[MF];
#pragma unroll
    for (int mf = 0; mf < MF; ++mf) {
      const int slot = mt * BM + wrow + mf * 16 + fr;
      const int idx = slot < n_e ? slot : 0;
      ab[mf] = AE + (size_t)idx * 32 + kg * 8;
    }

    f32x4 acc[MF][NF] = {};

#pragma unroll
    for (int pp = 0; pp < 2; ++pp) {
      const float* d = bdp + (size_t)(2 * pp * 16) * H_DIM;
      d0[pp] = *(const float4*)d;
      d1[pp] = *(const float4*)(d + H_DIM);
    }
#pragma unroll
    for (int pp = 0; pp < 2; ++pp) {
      const int k2 = 2 * (kp + pp * 16);
      *(uint32_t*)(&Bs[0][cg4 + 0][k2]) = pk2t(d0[pp].x, d1[pp].x);
      *(uint32_t*)(&Bs[0][cg4 + 1][k2]) = pk2t(d0[pp].y, d1[pp].y);
      *(uint32_t*)(&Bs[0][cg4 + 2][k2]) = pk2t(d0[pp].z, d1[pp].z);
      *(uint32_t*)(&Bs[0][cg4 + 3][k2]) = pk2t(d0[pp].w, d1[pp].w);
    }
    if (NS > 1) {
#pragma unroll
      for (int pp = 0; pp < 2; ++pp) {
        const float* d = bdp + (size_t)(BK + 2 * pp * 16) * H_DIM;
        d0[pp] = *(const float4*)d;
        d1[pp] = *(const float4*)(d + H_DIM);
      }
    }
    BAR();

    int b = 0;
    for (int s = 0; s < NS; ++s) {
      uint4 a[MF][2];
#pragma unroll
      for (int mf = 0; mf < MF; ++mf)
#pragma unroll
        for (int sl = 0; sl < 2; ++sl)
          a[mf][sl] = *(const uint4*)(ab[mf] + (size_t)(2 * s + sl) * ldA);
      if (s + 1 < NS) {
#pragma unroll
        for (int pp = 0; pp < 2; ++pp) {
          const int k2 = 2 * (kp + pp * 16);
          *(uint32_t*)(&Bs[b ^ 1][cg4 + 0][k2]) = pk2t(d0[pp].x, d1[pp].x);
          *(uint32_t*)(&Bs[b ^ 1][cg4 + 1][k2]) = pk2t(d0[pp].y, d1[pp].y);
          *(uint32_t*)(&Bs[b ^ 1][cg4 + 2][k2]) = pk2t(d0[pp].z, d1[pp].z);
          *(uint32_t*)(&Bs[b ^ 1][cg4 + 3][k2]) = pk2t(d0[pp].w, d1[pp].w);
        }
      }
      if (s + 2 < NS) {
#pragma unroll
        for (int pp = 0; pp < 2; ++pp) {
          const float* d = bdp + (size_t)((s + 2) * BK + 2 * pp * 16) * H_DIM;
          d0[pp] = *(const float4*)d;
          d1[pp] = *(const float4*)(d + H_DIM);
        }
      }
#pragma unroll
      for (int sl = 0; sl < 2; ++sl)
#pragma unroll
        for (int nf = 0; nf < NF; ++nf) {
          const bf16x8 bf_ = __builtin_bit_cast(
              bf16x8, *(const uint4*)(&Bs[b][nf * 16 + fr][kg * 8 + sl * 32]));
#pragma unroll
          for (int mf = 0; mf < MF; ++mf) {
            const bf16x8 af = __builtin_bit_cast(bf16x8, a[mf][sl]);
            acc[mf][nf] = __builtin_amdgcn_mfma_f32_16x16x32_bf16(
                af, bf_, acc[mf][nf], 0, 0, 0);
          }
        }
      BAR();
      b ^= 1;
    }

    const int col0 = nt * 64 + fr;
#pragma unroll
    for (int mf = 0; mf < MF; ++mf)
#pragma unroll
      for (int rr = 0; rr < 4; ++rr) {
        const int slot = mt * BM + wrow + mf * 16 + kg * 4 + rr;
        if constexpr (GATHER) {
          if (slot < n_e) {
            const int bv = bucket[e * CAPR + slot];
            const float w = bw[e * CAPR + slot];
            uint16_t* yb = (uint16_t*)outp + (size_t)bv * H_DIM + col0;
#pragma unroll
            for (int nf = 0; nf < NF; ++nf)
              yb[nf * 16] = f2bf(w * acc[mf][nf][rr]);
          }
        } else {
          float* op = (float*)outp + (size_t)slot * H_DIM + col0;
#pragma unroll
          for (int nf = 0; nf < NF; ++nf) op[nf * 16] = acc[mf][nf][rr];
        }
      }
  }
}

__global__ __launch_bounds__(256) void moe_down_k(
    const uint16_t* __restrict__ act, const float* __restrict__ Wd,
    uint16_t* __restrict__ ybuf, const int* __restrict__ cnt,
    const int* __restrict__ bucket, const float* __restrict__ bw) {
  __shared__ uint16_t Bs[2][64][LDP];
  ffn_down_body<256, true>(Bs, act, Wd, (void*)ybuf, cnt, bucket, bw, I_DIM,
                           CAPR, blockIdx.x);
}
__global__ __launch_bounds__(256) void dense_down_k(
    const uint16_t* __restrict__ s_actK, const float* __restrict__ sWd,
    float* __restrict__ shared_out, const int T) {
  __shared__ uint16_t Bs[2][64][LDP];
  ffn_down_body<128, false>(Bs, s_actK, sWd, (void*)shared_out, nullptr,
                            nullptr, nullptr, IS_DIM, T, blockIdx.x);
}

// ---------------- combine: routed[t] = sum_{j<k} ybuf[t*8+j] ----------------
__global__ __launch_bounds__(256) void combine_kernel(
    const uint16_t* __restrict__ ybuf, const int* __restrict__ topk_ptr,
    float* __restrict__ routed) {
  const int t = blockIdx.x;
  const int tid = threadIdx.x;
  int k = topk_ptr[0];
  if (k > TOPK_MAX) k = TOPK_MAX;
  float acc[8] = {};
  const uint16_t* base = ybuf + (size_t)t * 8 * H_DIM + tid * 8;
  for (int j = 0; j < k; ++j) {
    uint4 v = *(const uint4*)(base + (size_t)j * H_DIM);
    const uint16_t* h = (const uint16_t*)&v;
#pragma unroll
    for (int i = 0; i < 8; ++i) acc[i] += bf2f(h[i]);
  }
  float* op = routed + (size_t)t * H_DIM + tid * 8;
  *(float4*)op = make_float4(acc[0], acc[1], acc[2], acc[3]);
  *(float4*)(op + 4) = make_float4(acc[4], acc[5], acc[6], acc[7]);
}

extern "C" void kernel_launch(void* const* d_in, const int* in_sizes, int n_in,
                              void* d_out, int out_size, void* d_ws, size_t ws_size,
                              hipStream_t stream) {
  const float* x = (const float*)d_in[0];
  const float* gw = (const float*)d_in[1];
  const float* w_gate = (const float*)d_in[2];
  const float* w_up = (const float*)d_in[3];
  const float* w_down = (const float*)d_in[4];
  const float* sw_gate = (const float*)d_in[5];
  const float* sw_up = (const float*)d_in[6];
  const float* sw_down = (const float*)d_in[7];
  const int* topk = (const int*)d_in[8];
  const int T = in_sizes[0] / H_DIM;  // 2048

  float* shared_out = (float*)d_out;
  float* routed = shared_out + (size_t)T * H_DIM;

  char* ws = (char*)d_ws;
  size_t off = 0;
  auto take = [&](size_t b) {
    char* p = ws + off;
    off += (b + 255) & ~(size_t)255;
    return p;
  };
  uint16_t* xbK = (uint16_t*)take((size_t)T * H_DIM * 2);                      // 8.4 MB
  int* cnt = (int*)take(E_NUM * 4);
  int* bucket = (int*)take((size_t)E_NUM * CAPR * 4);
  float* bw = (float*)take((size_t)E_NUM * CAPR * 4);
  uint16_t* act = (uint16_t*)take((size_t)E_NUM * 16 * CAPR * 32 * 2 + 65536); // 18.9 MB
  uint16_t* s_actK = (uint16_t*)take((size_t)(IS_DIM / 32) * T * 32 * 2);      // 4.2 MB
  uint16_t* ybuf = (uint16_t*)take((size_t)T * 8 * H_DIM * 2);                 // 67 MB

  hipMemsetAsync(cnt, 0, E_NUM * 4, stream);

  router_kernel<<<T, 256, 0, stream>>>(x, gw, topk, cnt, bucket, bw, xbK, T);

  // grouped gate+up: A via bucket indirection into xbK (no gather pass)
  moe_in_k<<<E_NUM * (I_DIM / 32), 256, 0, stream>>>(xbK, w_gate, w_up, act,
                                                     cnt, bucket, T);
  // grouped down -> weighted bf16 rows in ybuf
  moe_down_k<<<E_NUM * (H_DIM / 64), 256, 0, stream>>>(act, w_down, ybuf, cnt,
                                                       bucket, bw);
  combine_kernel<<<T, 256, 0, stream>>>(ybuf, topk, routed);
  // shared expert
  dense_in_k<<<(IS_DIM / 32) * (T / 128), 256, 0, stream>>>(xbK, sw_gate,
                                                            sw_up, s_actK, T);
  dense_down_k<<<(H_DIM / 64) * (T / 128), 256, 0, stream>>>(s_actK, sw_down,
                                                             shared_out, T);
}